// Round 2
// baseline (1955.506 us; speedup 1.0000x reference)
//
#include <hip/hip_runtime.h>
#include <hip/hip_bf16.h>
#include <cstdint>
#include <cstddef>

#define N_NODES_C 19385
#define N_EDGES_C 1200000
#define GNN_C 256
#define HID_C 512
#define RANK_C 512
#define NCLS_C 3
#define NGENES_C 6640
#define NBLK_C 6
#define B_C 256
#define LN_EPS 1e-5f

// ---------------- CSR build ----------------

__global__ __launch_bounds__(256) void hist_kernel(const int* __restrict__ dst,
                                                   int* __restrict__ cnt, int E) {
  int i = blockIdx.x * 256 + threadIdx.x;
  if (i < E) atomicAdd(&cnt[dst[i]], 1);
}

__global__ __launch_bounds__(1024) void scan_kernel(const int* __restrict__ cnt,
                                                    int* __restrict__ off, int n) {
  __shared__ int sums[1024];
  const int t = threadIdx.x;
  const int CH = (n + 1023) >> 10;   // elements per thread
  const int base = t * CH;
  int s = 0;
  for (int i = 0; i < CH; ++i) {
    int idx = base + i;
    if (idx < n) s += cnt[idx];
  }
  sums[t] = s;
  __syncthreads();
  for (int d = 1; d < 1024; d <<= 1) {
    int v = (t >= d) ? sums[t - d] : 0;
    __syncthreads();
    sums[t] += v;
    __syncthreads();
  }
  int run = (t == 0) ? 0 : sums[t - 1];
  for (int i = 0; i < CH; ++i) {
    int idx = base + i;
    if (idx < n) { off[idx] = run; run += cnt[idx]; }
  }
  if (t == 0) off[n] = sums[1023];
}

// fill buckets with pre-gathered (src*GNN) and weight
__global__ __launch_bounds__(256) void fill_kernel(const int* __restrict__ src,
                                                   const int* __restrict__ dst,
                                                   const float* __restrict__ ew,
                                                   const int* __restrict__ off,
                                                   int* __restrict__ cur,
                                                   int* __restrict__ bsrc,
                                                   float* __restrict__ bw, int E) {
  int i = blockIdx.x * 256 + threadIdx.x;
  if (i < E) {
    int d = dst[i];
    int p = atomicAdd(&cur[d], 1);
    int q = off[d] + p;
    bsrc[q] = src[i] * GNN_C;
    bw[q] = ew[i];
  }
}

// ---------------- edge aggregation ----------------

// one block (256 thr) per node; thread t owns feature dim t
__global__ __launch_bounds__(256) void agg_full_kernel(const int* __restrict__ bsrc,
                                                       const float* __restrict__ bw,
                                                       const int* __restrict__ off,
                                                       const float* __restrict__ x,
                                                       float* __restrict__ agg) {
  __shared__ int ss[64];
  __shared__ float sw[64];
  const int n = blockIdx.x;
  const int t = threadIdx.x;
  const int s0 = off[n], s1 = off[n + 1];
  float acc = 0.f;
  for (int pos = s0; pos < s1; pos += 64) {
    const int cnt = min(64, s1 - pos);
    __syncthreads();
    if (t < cnt) { ss[t] = bsrc[pos + t]; sw[t] = bw[pos + t]; }
    __syncthreads();
    int j = 0;
    for (; j + 3 < cnt; j += 4) {
      const float x0 = x[ss[j + 0] + t];
      const float x1 = x[ss[j + 1] + t];
      const float x2 = x[ss[j + 2] + t];
      const float x3 = x[ss[j + 3] + t];
      acc = fmaf(x0, sw[j + 0], acc);
      acc = fmaf(x1, sw[j + 1], acc);
      acc = fmaf(x2, sw[j + 2], acc);
      acc = fmaf(x3, sw[j + 3], acc);
    }
    for (; j < cnt; ++j) acc = fmaf(x[ss[j] + t], sw[j], acc);
  }
  agg[(size_t)n * GNN_C + t] = acc;
}

// restricted aggregation: only the B gathered nodes (conv7)
__global__ __launch_bounds__(256) void agg_sel_kernel(const int* __restrict__ node_idx,
                                                      const int* __restrict__ bsrc,
                                                      const float* __restrict__ bw,
                                                      const int* __restrict__ off,
                                                      const float* __restrict__ x,
                                                      float* __restrict__ agg) {
  __shared__ int ss[64];
  __shared__ float sw[64];
  const int b = blockIdx.x;
  const int t = threadIdx.x;
  const int n = max(node_idx[b], 0);
  const int s0 = off[n], s1 = off[n + 1];
  float acc = 0.f;
  for (int pos = s0; pos < s1; pos += 64) {
    const int cnt = min(64, s1 - pos);
    __syncthreads();
    if (t < cnt) { ss[t] = bsrc[pos + t]; sw[t] = bw[pos + t]; }
    __syncthreads();
    int j = 0;
    for (; j + 3 < cnt; j += 4) {
      const float x0 = x[ss[j + 0] + t];
      const float x1 = x[ss[j + 1] + t];
      const float x2 = x[ss[j + 2] + t];
      const float x3 = x[ss[j + 3] + t];
      acc = fmaf(x0, sw[j + 0], acc);
      acc = fmaf(x1, sw[j + 1], acc);
      acc = fmaf(x2, sw[j + 2], acc);
      acc = fmaf(x3, sw[j + 3], acc);
    }
    for (; j < cnt; ++j) acc = fmaf(x[ss[j] + t], sw[j], acc);
  }
  agg[(size_t)b * GNN_C + t] = acc;
}

// ---------------- generic GEMM: C = A[MxK] * B (+bias)(+gelu)(+resid), all fp32 ----------------
// tile 64x64, KC=32, 256 threads, 4x4 microtile / thread

#define KC 32

__global__ __launch_bounds__(256) void gemm_kernel(const float* __restrict__ A,
                                                   const float* __restrict__ B,
                                                   const float* __restrict__ bias,
                                                   const float* resid,
                                                   float* __restrict__ C,
                                                   int M, int N, int K,
                                                   int transB, int doGelu) {
  __shared__ float As[KC][72];
  __shared__ float Bs[KC][72];
  const int t = threadIdx.x;
  const int r0 = blockIdx.x * 64;
  const int c0 = blockIdx.y * 64;
  const int tx = t & 15;        // col quad
  const int ty = t >> 4;        // row quad
  float acc[4][4] = {{0.f}};

  for (int k0 = 0; k0 < K; k0 += KC) {
    // A tile: thread loads 8 contiguous fp32 of row (t>>2), k offset (t&3)*8
    {
      const int ra = t >> 2;
      const int kk = (t & 3) * 8;
      const int gr = r0 + ra;
      float4 v0, v1;
      if (gr < M) {
        const float4* p = reinterpret_cast<const float4*>(A + (size_t)gr * K + k0 + kk);
        v0 = p[0]; v1 = p[1];
      } else {
        v0 = make_float4(0.f, 0.f, 0.f, 0.f); v1 = v0;
      }
      As[kk + 0][ra] = v0.x; As[kk + 1][ra] = v0.y;
      As[kk + 2][ra] = v0.z; As[kk + 3][ra] = v0.w;
      As[kk + 4][ra] = v1.x; As[kk + 5][ra] = v1.y;
      As[kk + 6][ra] = v1.z; As[kk + 7][ra] = v1.w;
    }
    if (!transB) {
      // B[k][n] row-major: thread loads 4 contig fp32 at (kk, c) for 2 kk values
      const int c = (t & 15) * 4;
      const int kk = (t >> 4) * 2;
      for (int j = 0; j < 2; ++j) {
        const int gk = k0 + kk + j;
        const int gc = c0 + c;
        float4 bv;
        if (gc + 3 < N) {
          bv = *reinterpret_cast<const float4*>(B + (size_t)gk * N + gc);
        } else {
          bv.x = (gc + 0 < N) ? B[(size_t)gk * N + gc + 0] : 0.f;
          bv.y = (gc + 1 < N) ? B[(size_t)gk * N + gc + 1] : 0.f;
          bv.z = (gc + 2 < N) ? B[(size_t)gk * N + gc + 2] : 0.f;
          bv.w = (gc + 3 < N) ? B[(size_t)gk * N + gc + 3] : 0.f;
        }
        *reinterpret_cast<float4*>(&Bs[kk + j][c]) = bv;
      }
    } else {
      // B is [N,K] row-major (gene emb): Bs[kk][c] = B[c][kk]
      const int c = t >> 2;
      const int kk = (t & 3) * 8;
      const int gc = c0 + c;
      if (gc < N) {
        const float4* p = reinterpret_cast<const float4*>(B + (size_t)gc * K + k0 + kk);
        float4 v0 = p[0], v1 = p[1];
        Bs[kk + 0][c] = v0.x; Bs[kk + 1][c] = v0.y;
        Bs[kk + 2][c] = v0.z; Bs[kk + 3][c] = v0.w;
        Bs[kk + 4][c] = v1.x; Bs[kk + 5][c] = v1.y;
        Bs[kk + 6][c] = v1.z; Bs[kk + 7][c] = v1.w;
      } else {
        for (int j = 0; j < 8; ++j) Bs[kk + j][c] = 0.f;
      }
    }
    __syncthreads();
#pragma unroll
    for (int kk = 0; kk < KC; ++kk) {
      const float4 a = *reinterpret_cast<const float4*>(&As[kk][ty * 4]);
      const float4 b = *reinterpret_cast<const float4*>(&Bs[kk][tx * 4]);
      acc[0][0] = fmaf(a.x, b.x, acc[0][0]);
      acc[0][1] = fmaf(a.x, b.y, acc[0][1]);
      acc[0][2] = fmaf(a.x, b.z, acc[0][2]);
      acc[0][3] = fmaf(a.x, b.w, acc[0][3]);
      acc[1][0] = fmaf(a.y, b.x, acc[1][0]);
      acc[1][1] = fmaf(a.y, b.y, acc[1][1]);
      acc[1][2] = fmaf(a.y, b.z, acc[1][2]);
      acc[1][3] = fmaf(a.y, b.w, acc[1][3]);
      acc[2][0] = fmaf(a.z, b.x, acc[2][0]);
      acc[2][1] = fmaf(a.z, b.y, acc[2][1]);
      acc[2][2] = fmaf(a.z, b.z, acc[2][2]);
      acc[2][3] = fmaf(a.z, b.w, acc[2][3]);
      acc[3][0] = fmaf(a.w, b.x, acc[3][0]);
      acc[3][1] = fmaf(a.w, b.y, acc[3][1]);
      acc[3][2] = fmaf(a.w, b.z, acc[3][2]);
      acc[3][3] = fmaf(a.w, b.w, acc[3][3]);
    }
    __syncthreads();
  }

  // epilogue
  for (int i = 0; i < 4; ++i) {
    const int row = r0 + ty * 4 + i;
    if (row >= M) continue;
    for (int j = 0; j < 4; ++j) {
      const int col = c0 + tx * 4 + j;
      if (col >= N) continue;
      float v = acc[i][j];
      if (bias) v += bias[col];
      if (doGelu) {
        const float x3 = v * v * v;
        v = 0.5f * v * (1.f + tanhf(0.7978845608028654f * (v + 0.044715f * x3)));
      }
      if (resid) v += resid[(size_t)row * N + col];
      C[(size_t)row * N + col] = v;
    }
  }
}

// ---------------- LN family ----------------

// x1 = frozen + relu(ln(y6));  C=256, 256 thr/row.
__global__ __launch_bounds__(256) void postconv6_kernel(const float* __restrict__ y,
                                                        const float* __restrict__ g,
                                                        const float* __restrict__ b,
                                                        const float* __restrict__ frozen,
                                                        float* __restrict__ x1f) {
  __shared__ float sb[4];
  const int n = blockIdx.x, t = threadIdx.x;
  const float v = y[(size_t)n * GNN_C + t];
  float s = v;
  for (int o = 32; o; o >>= 1) s += __shfl_down(s, o, 64);
  if ((t & 63) == 0) sb[t >> 6] = s;
  __syncthreads();
  const float m = (sb[0] + sb[1] + sb[2] + sb[3]) * (1.f / GNN_C);
  __syncthreads();
  const float d = v - m;
  s = d * d;
  for (int o = 32; o; o >>= 1) s += __shfl_down(s, o, 64);
  if ((t & 63) == 0) sb[t >> 6] = s;
  __syncthreads();
  const float rs = rsqrtf((sb[0] + sb[1] + sb[2] + sb[3]) * (1.f / GNN_C) + LN_EPS);
  const float xn = d * rs * g[t] + b[t];
  x1f[(size_t)n * GNN_C + t] = frozen[(size_t)n * GNN_C + t] + fmaxf(xn, 0.f);
}

// x2_b = x1[n_b] + relu(ln(y7_b))
__global__ __launch_bounds__(256) void postconv7_kernel(const float* __restrict__ y,
                                                        const float* __restrict__ g,
                                                        const float* __restrict__ b,
                                                        const int* __restrict__ idx,
                                                        const float* __restrict__ x1f,
                                                        float* __restrict__ out) {
  __shared__ float sb[4];
  const int bi = blockIdx.x, t = threadIdx.x;
  const int n = max(idx[bi], 0);
  const float v = y[(size_t)bi * GNN_C + t];
  float s = v;
  for (int o = 32; o; o >>= 1) s += __shfl_down(s, o, 64);
  if ((t & 63) == 0) sb[t >> 6] = s;
  __syncthreads();
  const float m = (sb[0] + sb[1] + sb[2] + sb[3]) * (1.f / GNN_C);
  __syncthreads();
  const float d = v - m;
  s = d * d;
  for (int o = 32; o; o >>= 1) s += __shfl_down(s, o, 64);
  if ((t & 63) == 0) sb[t >> 6] = s;
  __syncthreads();
  const float rs = rsqrtf((sb[0] + sb[1] + sb[2] + sb[3]) * (1.f / GNN_C) + LN_EPS);
  const float xn = d * rs * g[t] + b[t];
  out[(size_t)bi * GNN_C + t] = x1f[(size_t)n * GNN_C + t] + fmaxf(xn, 0.f);
}

// h0 = (idx>=0 ? node_emb[b] : oov); out = ln(h0)*g+b   (C=256)
__global__ __launch_bounds__(256) void h0ln_kernel(const float* __restrict__ ne,
                                                   const int* __restrict__ idx,
                                                   const float* __restrict__ oov,
                                                   const float* __restrict__ g,
                                                   const float* __restrict__ b,
                                                   float* __restrict__ out) {
  __shared__ float sb[4];
  const int bi = blockIdx.x, t = threadIdx.x;
  const float v = (idx[bi] >= 0) ? ne[(size_t)bi * GNN_C + t] : oov[t];
  float s = v;
  for (int o = 32; o; o >>= 1) s += __shfl_down(s, o, 64);
  if ((t & 63) == 0) sb[t >> 6] = s;
  __syncthreads();
  const float m = (sb[0] + sb[1] + sb[2] + sb[3]) * (1.f / GNN_C);
  __syncthreads();
  const float d = v - m;
  s = d * d;
  for (int o = 32; o; o >>= 1) s += __shfl_down(s, o, 64);
  if ((t & 63) == 0) sb[t >> 6] = s;
  __syncthreads();
  const float rs = rsqrtf((sb[0] + sb[1] + sb[2] + sb[3]) * (1.f / GNN_C) + LN_EPS);
  out[(size_t)bi * GNN_C + t] = d * rs * g[t] + b[t];
}

// ln over C=512 rows (residual blocks & out_ln); 256 thr, 2 elems/thr
__global__ __launch_bounds__(256) void ln512_kernel(const float* __restrict__ in,
                                                    const float* __restrict__ g,
                                                    const float* __restrict__ b,
                                                    float* __restrict__ out) {
  __shared__ float sb[4];
  const int r = blockIdx.x, t = threadIdx.x;
  const float v0 = in[(size_t)r * HID_C + t];
  const float v1 = in[(size_t)r * HID_C + t + 256];
  float s = v0 + v1;
  for (int o = 32; o; o >>= 1) s += __shfl_down(s, o, 64);
  if ((t & 63) == 0) sb[t >> 6] = s;
  __syncthreads();
  const float m = (sb[0] + sb[1] + sb[2] + sb[3]) * (1.f / HID_C);
  __syncthreads();
  const float d0 = v0 - m, d1 = v1 - m;
  s = d0 * d0 + d1 * d1;
  for (int o = 32; o; o >>= 1) s += __shfl_down(s, o, 64);
  if ((t & 63) == 0) sb[t >> 6] = s;
  __syncthreads();
  const float rs = rsqrtf((sb[0] + sb[1] + sb[2] + sb[3]) * (1.f / HID_C) + LN_EPS);
  out[(size_t)r * HID_C + t] = d0 * rs * g[t] + b[t];
  out[(size_t)r * HID_C + t + 256] = d1 * rs * g[t + 256] + b[t + 256];
}

// ---------------- host ----------------

extern "C" void kernel_launch(void* const* d_in, const int* in_sizes, int n_in,
                              void* d_out, int out_size, void* d_ws, size_t ws_size,
                              hipStream_t stream) {
  const int* node_idx = (const int*)d_in[0];
  const int* e_src = (const int*)d_in[1];
  const int* e_dst = e_src + N_EDGES_C;
  const float* ew = (const float*)d_in[2];
  const float* frozen = (const float*)d_in[3];
  const float* W6 = (const float*)d_in[4];
  const float* b6 = (const float*)d_in[5];
  const float* g6 = (const float*)d_in[6];
  const float* bl6 = (const float*)d_in[7];
  const float* W7 = (const float*)d_in[8];
  const float* b7 = (const float*)d_in[9];
  const float* g7 = (const float*)d_in[10];
  const float* bl7 = (const float*)d_in[11];
  const float* postW = (const float*)d_in[12];
  const float* postb = (const float*)d_in[13];
  const float* oov = (const float*)d_in[14];
  const float* ing = (const float*)d_in[15];
  const float* inb = (const float*)d_in[16];
  const float* projW = (const float*)d_in[17];
  const float* projb = (const float*)d_in[18];
  const float* rbg = (const float*)d_in[19];
  const float* rbb = (const float*)d_in[20];
  const float* rbW1 = (const float*)d_in[21];
  const float* rbb1 = (const float*)d_in[22];
  const float* rbW2 = (const float*)d_in[23];
  const float* rbb2 = (const float*)d_in[24];
  const float* outg = (const float*)d_in[25];
  const float* outb = (const float*)d_in[26];
  const float* bilW = (const float*)d_in[27];
  const float* bilb = (const float*)d_in[28];
  const float* gene = (const float*)d_in[29];
  (void)in_sizes; (void)n_in; (void)out_size; (void)ws_size;

  char* ws = (char*)d_ws;
  size_t o = 0;
  auto alloc = [&](size_t bytes) -> char* {
    char* p = ws + o;
    o += (bytes + 255) & ~(size_t)255;
    return p;
  };
  int* cnt = (int*)alloc((size_t)N_NODES_C * 4);
  int* off = (int*)alloc((size_t)(N_NODES_C + 1) * 4);
  int* cur = (int*)alloc((size_t)N_NODES_C * 4);
  int* bsrc = (int*)alloc((size_t)N_EDGES_C * 4);
  float* bw = (float*)alloc((size_t)N_EDGES_C * 4);
  float* agg6 = (float*)alloc((size_t)N_NODES_C * GNN_C * 4);
  float* y6 = (float*)alloc((size_t)N_NODES_C * GNN_C * 4);
  float* agg7b = (float*)alloc((size_t)B_C * GNN_C * 4);
  float* y7b = (float*)alloc((size_t)B_C * GNN_C * 4);
  float* x2b = (float*)alloc((size_t)B_C * GNN_C * 4);
  float* nemb = (float*)alloc((size_t)B_C * GNN_C * 4);
  float* h0l = (float*)alloc((size_t)B_C * GNN_C * 4);
  float* h = (float*)alloc((size_t)B_C * HID_C * 4);
  float* tb = (float*)alloc((size_t)B_C * HID_C * 4);
  float* u = (float*)alloc((size_t)B_C * 4 * HID_C * 4);
  float* hl = (float*)alloc((size_t)B_C * HID_C * 4);
  float* pert = (float*)alloc((size_t)B_C * NCLS_C * RANK_C * 4);
  float* x1f = agg6;  // alias: agg6 dead after conv6 GEMM

  // CSR build
  (void)hipMemsetAsync(cnt, 0, (size_t)N_NODES_C * 4, stream);
  (void)hipMemsetAsync(cur, 0, (size_t)N_NODES_C * 4, stream);
  const int egrid = (N_EDGES_C + 255) / 256;
  hist_kernel<<<egrid, 256, 0, stream>>>(e_dst, cnt, N_EDGES_C);
  scan_kernel<<<1, 1024, 0, stream>>>(cnt, off, N_NODES_C);
  fill_kernel<<<egrid, 256, 0, stream>>>(e_src, e_dst, ew, off, cur, bsrc, bw, N_EDGES_C);

  // conv6 (full graph)
  agg_full_kernel<<<N_NODES_C, 256, 0, stream>>>(bsrc, bw, off, frozen, agg6);
  {
    dim3 g((N_NODES_C + 63) / 64, GNN_C / 64);
    gemm_kernel<<<g, 256, 0, stream>>>(agg6, W6, b6, nullptr, y6,
                                       N_NODES_C, GNN_C, GNN_C, 0, 0);
  }
  postconv6_kernel<<<N_NODES_C, 256, 0, stream>>>(y6, g6, bl6, frozen, x1f);

  // conv7 (only the B gathered nodes)
  agg_sel_kernel<<<B_C, 256, 0, stream>>>(node_idx, bsrc, bw, off, x1f, agg7b);
  {
    dim3 g(B_C / 64, GNN_C / 64);
    gemm_kernel<<<g, 256, 0, stream>>>(agg7b, W7, b7, nullptr, y7b,
                                       B_C, GNN_C, GNN_C, 0, 0);
  }
  postconv7_kernel<<<B_C, 256, 0, stream>>>(y7b, g7, bl7, node_idx, x1f, x2b);

  // node_emb = x2 @ post_W + post_b (B rows only)
  {
    dim3 g(B_C / 64, GNN_C / 64);
    gemm_kernel<<<g, 256, 0, stream>>>(x2b, postW, postb, nullptr, nemb,
                                       B_C, GNN_C, GNN_C, 0, 0);
  }
  h0ln_kernel<<<B_C, 256, 0, stream>>>(nemb, node_idx, oov, ing, inb, h0l);

  // proj_in
  {
    dim3 g(B_C / 64, HID_C / 64);
    gemm_kernel<<<g, 256, 0, stream>>>(h0l, projW, projb, nullptr, h,
                                       B_C, HID_C, GNN_C, 0, 0);
  }

  // residual blocks
  for (int i = 0; i < NBLK_C; ++i) {
    ln512_kernel<<<B_C, 256, 0, stream>>>(h, rbg + (size_t)i * HID_C,
                                          rbb + (size_t)i * HID_C, tb);
    dim3 g1(B_C / 64, (4 * HID_C) / 64);
    gemm_kernel<<<g1, 256, 0, stream>>>(tb, rbW1 + (size_t)i * HID_C * 4 * HID_C,
                                        rbb1 + (size_t)i * 4 * HID_C, nullptr, u,
                                        B_C, 4 * HID_C, HID_C, 0, 1);
    dim3 g2(B_C / 64, HID_C / 64);
    gemm_kernel<<<g2, 256, 0, stream>>>(u, rbW2 + (size_t)i * 4 * HID_C * HID_C,
                                        rbb2 + (size_t)i * HID_C, h, h,
                                        B_C, HID_C, 4 * HID_C, 0, 0);
  }

  // out_ln + bilinear
  ln512_kernel<<<B_C, 256, 0, stream>>>(h, outg, outb, hl);
  {
    dim3 g(B_C / 64, (NCLS_C * RANK_C) / 64);
    gemm_kernel<<<g, 256, 0, stream>>>(hl, bilW, bilb, nullptr, pert,
                                       B_C, NCLS_C * RANK_C, HID_C, 0, 0);
  }

  // logits = pert([768,512]) @ gene^T ([512,6640]) -> fp32 d_out
  {
    dim3 g((B_C * NCLS_C + 63) / 64, (NGENES_C + 63) / 64);
    gemm_kernel<<<g, 256, 0, stream>>>(pert, gene, nullptr, nullptr,
                                       (float*)d_out, B_C * NCLS_C, NGENES_C, RANK_C, 1, 0);
  }
}

// Round 3
// 1006.514 us; speedup vs baseline: 1.9428x; 1.9428x over previous
//
#include <hip/hip_runtime.h>
#include <hip/hip_bf16.h>
#include <cstdint>
#include <cstddef>

#define N_NODES_C 19385
#define N_EDGES_C 1200000
#define GNN_C 256
#define HID_C 512
#define RANK_C 512
#define NCLS_C 3
#define NGENES_C 6640
#define NBLK_C 6
#define B_C 256
#define LN_EPS 1e-5f

// ---------------- CSR build ----------------

__global__ __launch_bounds__(256) void hist_kernel(const int* __restrict__ dst,
                                                   int* __restrict__ cnt, int E) {
  int i = blockIdx.x * 256 + threadIdx.x;
  if (i < E) atomicAdd(&cnt[dst[i]], 1);
}

__global__ __launch_bounds__(1024) void scan_kernel(const int* __restrict__ cnt,
                                                    int* __restrict__ off, int n) {
  __shared__ int sums[1024];
  const int t = threadIdx.x;
  const int CH = (n + 1023) >> 10;   // elements per thread
  const int base = t * CH;
  int s = 0;
  for (int i = 0; i < CH; ++i) {
    int idx = base + i;
    if (idx < n) s += cnt[idx];
  }
  sums[t] = s;
  __syncthreads();
  for (int d = 1; d < 1024; d <<= 1) {
    int v = (t >= d) ? sums[t - d] : 0;
    __syncthreads();
    sums[t] += v;
    __syncthreads();
  }
  int run = (t == 0) ? 0 : sums[t - 1];
  for (int i = 0; i < CH; ++i) {
    int idx = base + i;
    if (idx < n) { off[idx] = run; run += cnt[idx]; }
  }
  if (t == 0) off[n] = sums[1023];
}

// fill buckets with pre-gathered (src*GNN) and weight
__global__ __launch_bounds__(256) void fill_kernel(const int* __restrict__ src,
                                                   const int* __restrict__ dst,
                                                   const float* __restrict__ ew,
                                                   const int* __restrict__ off,
                                                   int* __restrict__ cur,
                                                   int* __restrict__ bsrc,
                                                   float* __restrict__ bw, int E) {
  int i = blockIdx.x * 256 + threadIdx.x;
  if (i < E) {
    int d = dst[i];
    int p = atomicAdd(&cur[d], 1);
    int q = off[d] + p;
    bsrc[q] = src[i] * GNN_C;
    bw[q] = ew[i];
  }
}

// ---------------- edge aggregation ----------------

__global__ __launch_bounds__(256) void agg_full_kernel(const int* __restrict__ bsrc,
                                                       const float* __restrict__ bw,
                                                       const int* __restrict__ off,
                                                       const float* __restrict__ x,
                                                       float* __restrict__ agg) {
  __shared__ int ss[64];
  __shared__ float sw[64];
  const int n = blockIdx.x;
  const int t = threadIdx.x;
  const int s0 = off[n], s1 = off[n + 1];
  float acc = 0.f;
  for (int pos = s0; pos < s1; pos += 64) {
    const int cnt = min(64, s1 - pos);
    __syncthreads();
    if (t < cnt) { ss[t] = bsrc[pos + t]; sw[t] = bw[pos + t]; }
    __syncthreads();
    int j = 0;
    for (; j + 3 < cnt; j += 4) {
      const float x0 = x[ss[j + 0] + t];
      const float x1 = x[ss[j + 1] + t];
      const float x2 = x[ss[j + 2] + t];
      const float x3 = x[ss[j + 3] + t];
      acc = fmaf(x0, sw[j + 0], acc);
      acc = fmaf(x1, sw[j + 1], acc);
      acc = fmaf(x2, sw[j + 2], acc);
      acc = fmaf(x3, sw[j + 3], acc);
    }
    for (; j < cnt; ++j) acc = fmaf(x[ss[j] + t], sw[j], acc);
  }
  agg[(size_t)n * GNN_C + t] = acc;
}

__global__ __launch_bounds__(256) void agg_sel_kernel(const int* __restrict__ node_idx,
                                                      const int* __restrict__ bsrc,
                                                      const float* __restrict__ bw,
                                                      const int* __restrict__ off,
                                                      const float* __restrict__ x,
                                                      float* __restrict__ agg) {
  __shared__ int ss[64];
  __shared__ float sw[64];
  const int b = blockIdx.x;
  const int t = threadIdx.x;
  const int n = max(node_idx[b], 0);
  const int s0 = off[n], s1 = off[n + 1];
  float acc = 0.f;
  for (int pos = s0; pos < s1; pos += 64) {
    const int cnt = min(64, s1 - pos);
    __syncthreads();
    if (t < cnt) { ss[t] = bsrc[pos + t]; sw[t] = bw[pos + t]; }
    __syncthreads();
    int j = 0;
    for (; j + 3 < cnt; j += 4) {
      const float x0 = x[ss[j + 0] + t];
      const float x1 = x[ss[j + 1] + t];
      const float x2 = x[ss[j + 2] + t];
      const float x3 = x[ss[j + 3] + t];
      acc = fmaf(x0, sw[j + 0], acc);
      acc = fmaf(x1, sw[j + 1], acc);
      acc = fmaf(x2, sw[j + 2], acc);
      acc = fmaf(x3, sw[j + 3], acc);
    }
    for (; j < cnt; ++j) acc = fmaf(x[ss[j] + t], sw[j], acc);
  }
  agg[(size_t)b * GNN_C + t] = acc;
}

// ---------------- GEMM core macro-tile: 64x64, KC=32, 4x4/thread ----------------

#define KC 32

__device__ __forceinline__ void gemm_tile_body(const float* __restrict__ A,
                                               const float* __restrict__ B,
                                               int M, int N, int K,
                                               int r0, int c0, int kBeg, int kEnd,
                                               int transB, int t,
                                               float (&acc)[4][4],
                                               float (*As)[72], float (*Bs)[72]) {
  const int tx = t & 15;
  const int ty = t >> 4;
  for (int k0 = kBeg; k0 < kEnd; k0 += KC) {
    {
      const int ra = t >> 2;
      const int kk = (t & 3) * 8;
      const int gr = r0 + ra;
      float4 v0, v1;
      if (gr < M) {
        const float4* p = reinterpret_cast<const float4*>(A + (size_t)gr * K + k0 + kk);
        v0 = p[0]; v1 = p[1];
      } else {
        v0 = make_float4(0.f, 0.f, 0.f, 0.f); v1 = v0;
      }
      As[kk + 0][ra] = v0.x; As[kk + 1][ra] = v0.y;
      As[kk + 2][ra] = v0.z; As[kk + 3][ra] = v0.w;
      As[kk + 4][ra] = v1.x; As[kk + 5][ra] = v1.y;
      As[kk + 6][ra] = v1.z; As[kk + 7][ra] = v1.w;
    }
    if (!transB) {
      const int c = (t & 15) * 4;
      const int kk = (t >> 4) * 2;
      for (int j = 0; j < 2; ++j) {
        const int gk = k0 + kk + j;
        const int gc = c0 + c;
        float4 bv;
        if (gc + 3 < N) {
          bv = *reinterpret_cast<const float4*>(B + (size_t)gk * N + gc);
        } else {
          bv.x = (gc + 0 < N) ? B[(size_t)gk * N + gc + 0] : 0.f;
          bv.y = (gc + 1 < N) ? B[(size_t)gk * N + gc + 1] : 0.f;
          bv.z = (gc + 2 < N) ? B[(size_t)gk * N + gc + 2] : 0.f;
          bv.w = (gc + 3 < N) ? B[(size_t)gk * N + gc + 3] : 0.f;
        }
        *reinterpret_cast<float4*>(&Bs[kk + j][c]) = bv;
      }
    } else {
      const int c = t >> 2;
      const int kk = (t & 3) * 8;
      const int gc = c0 + c;
      if (gc < N) {
        const float4* p = reinterpret_cast<const float4*>(B + (size_t)gc * K + k0 + kk);
        float4 v0 = p[0], v1 = p[1];
        Bs[kk + 0][c] = v0.x; Bs[kk + 1][c] = v0.y;
        Bs[kk + 2][c] = v0.z; Bs[kk + 3][c] = v0.w;
        Bs[kk + 4][c] = v1.x; Bs[kk + 5][c] = v1.y;
        Bs[kk + 6][c] = v1.z; Bs[kk + 7][c] = v1.w;
      } else {
        for (int j = 0; j < 8; ++j) Bs[kk + j][c] = 0.f;
      }
    }
    __syncthreads();
#pragma unroll
    for (int kk = 0; kk < KC; ++kk) {
      const float4 a = *reinterpret_cast<const float4*>(&As[kk][ty * 4]);
      const float4 b = *reinterpret_cast<const float4*>(&Bs[kk][tx * 4]);
      acc[0][0] = fmaf(a.x, b.x, acc[0][0]);
      acc[0][1] = fmaf(a.x, b.y, acc[0][1]);
      acc[0][2] = fmaf(a.x, b.z, acc[0][2]);
      acc[0][3] = fmaf(a.x, b.w, acc[0][3]);
      acc[1][0] = fmaf(a.y, b.x, acc[1][0]);
      acc[1][1] = fmaf(a.y, b.y, acc[1][1]);
      acc[1][2] = fmaf(a.y, b.z, acc[1][2]);
      acc[1][3] = fmaf(a.y, b.w, acc[1][3]);
      acc[2][0] = fmaf(a.z, b.x, acc[2][0]);
      acc[2][1] = fmaf(a.z, b.y, acc[2][1]);
      acc[2][2] = fmaf(a.z, b.z, acc[2][2]);
      acc[2][3] = fmaf(a.z, b.w, acc[2][3]);
      acc[3][0] = fmaf(a.w, b.x, acc[3][0]);
      acc[3][1] = fmaf(a.w, b.y, acc[3][1]);
      acc[3][2] = fmaf(a.w, b.z, acc[3][2]);
      acc[3][3] = fmaf(a.w, b.w, acc[3][3]);
    }
    __syncthreads();
  }
}

// direct GEMM with fused epilogue (for large grids: conv6, gene)
__global__ __launch_bounds__(256) void gemm_kernel(const float* __restrict__ A,
                                                   const float* __restrict__ B,
                                                   const float* __restrict__ bias,
                                                   const float* resid,
                                                   float* __restrict__ C,
                                                   int M, int N, int K,
                                                   int transB, int doGelu) {
  __shared__ float As[KC][72];
  __shared__ float Bs[KC][72];
  const int t = threadIdx.x;
  const int r0 = blockIdx.x * 64;
  const int c0 = blockIdx.y * 64;
  float acc[4][4] = {{0.f}};
  gemm_tile_body(A, B, M, N, K, r0, c0, 0, K, transB, t, acc, As, Bs);
  const int tx = t & 15, ty = t >> 4;
  for (int i = 0; i < 4; ++i) {
    const int row = r0 + ty * 4 + i;
    if (row >= M) continue;
    for (int j = 0; j < 4; ++j) {
      const int col = c0 + tx * 4 + j;
      if (col >= N) continue;
      float v = acc[i][j];
      if (bias) v += bias[col];
      if (doGelu) {
        const float x3 = v * v * v;
        v = 0.5f * v * (1.f + tanhf(0.7978845608028654f * (v + 0.044715f * x3)));
      }
      if (resid) v += resid[(size_t)row * N + col];
      C[(size_t)row * N + col] = v;
    }
  }
}

// split-K GEMM: grid.z = S slices; writes raw partials part[z][M][N]
__global__ __launch_bounds__(256) void skgemm_kernel(const float* __restrict__ A,
                                                     const float* __restrict__ B,
                                                     float* __restrict__ part,
                                                     int M, int N, int K, int kChunk) {
  __shared__ float As[KC][72];
  __shared__ float Bs[KC][72];
  const int t = threadIdx.x;
  const int r0 = blockIdx.x * 64;
  const int c0 = blockIdx.y * 64;
  const int kBeg = blockIdx.z * kChunk;
  const int kEnd = min(K, kBeg + kChunk);
  float acc[4][4] = {{0.f}};
  gemm_tile_body(A, B, M, N, K, r0, c0, kBeg, kEnd, 0, t, acc, As, Bs);
  float* out = part + (size_t)blockIdx.z * M * N;
  const int tx = t & 15, ty = t >> 4;
  for (int i = 0; i < 4; ++i) {
    const int row = r0 + ty * 4 + i;
    for (int j = 0; j < 4; ++j) {
      const int col = c0 + tx * 4 + j;
      out[(size_t)row * N + col] = acc[i][j];
    }
  }
}

// combine S partials + bias, then op: 0=none, 1=gelu, 2=add resid (resid==out ok)
__global__ __launch_bounds__(256) void combine_kernel(const float* __restrict__ part,
                                                      int S, int MN, int N,
                                                      const float* __restrict__ bias,
                                                      const float* __restrict__ resid,
                                                      float* __restrict__ out, int op) {
  int i = blockIdx.x * 256 + threadIdx.x;
  if (i >= MN) return;
  float v = 0.f;
  for (int s = 0; s < S; ++s) v += part[(size_t)s * MN + i];
  v += bias[i - (i / N) * N];
  if (op == 1) {
    const float x3 = v * v * v;
    v = 0.5f * v * (1.f + tanhf(0.7978845608028654f * (v + 0.044715f * x3)));
  } else if (op == 2) {
    v += resid[i];
  }
  out[i] = v;
}

// ---------------- LN family ----------------

__global__ __launch_bounds__(256) void postconv6_kernel(const float* __restrict__ y,
                                                        const float* __restrict__ g,
                                                        const float* __restrict__ b,
                                                        const float* __restrict__ frozen,
                                                        float* __restrict__ x1f) {
  __shared__ float sb[4];
  const int n = blockIdx.x, t = threadIdx.x;
  const float v = y[(size_t)n * GNN_C + t];
  float s = v;
  for (int o = 32; o; o >>= 1) s += __shfl_down(s, o, 64);
  if ((t & 63) == 0) sb[t >> 6] = s;
  __syncthreads();
  const float m = (sb[0] + sb[1] + sb[2] + sb[3]) * (1.f / GNN_C);
  __syncthreads();
  const float d = v - m;
  s = d * d;
  for (int o = 32; o; o >>= 1) s += __shfl_down(s, o, 64);
  if ((t & 63) == 0) sb[t >> 6] = s;
  __syncthreads();
  const float rs = rsqrtf((sb[0] + sb[1] + sb[2] + sb[3]) * (1.f / GNN_C) + LN_EPS);
  const float xn = d * rs * g[t] + b[t];
  x1f[(size_t)n * GNN_C + t] = frozen[(size_t)n * GNN_C + t] + fmaxf(xn, 0.f);
}

__global__ __launch_bounds__(256) void postconv7_kernel(const float* __restrict__ y,
                                                        const float* __restrict__ g,
                                                        const float* __restrict__ b,
                                                        const int* __restrict__ idx,
                                                        const float* __restrict__ x1f,
                                                        float* __restrict__ out) {
  __shared__ float sb[4];
  const int bi = blockIdx.x, t = threadIdx.x;
  const int n = max(idx[bi], 0);
  const float v = y[(size_t)bi * GNN_C + t];
  float s = v;
  for (int o = 32; o; o >>= 1) s += __shfl_down(s, o, 64);
  if ((t & 63) == 0) sb[t >> 6] = s;
  __syncthreads();
  const float m = (sb[0] + sb[1] + sb[2] + sb[3]) * (1.f / GNN_C);
  __syncthreads();
  const float d = v - m;
  s = d * d;
  for (int o = 32; o; o >>= 1) s += __shfl_down(s, o, 64);
  if ((t & 63) == 0) sb[t >> 6] = s;
  __syncthreads();
  const float rs = rsqrtf((sb[0] + sb[1] + sb[2] + sb[3]) * (1.f / GNN_C) + LN_EPS);
  const float xn = d * rs * g[t] + b[t];
  out[(size_t)bi * GNN_C + t] = x1f[(size_t)n * GNN_C + t] + fmaxf(xn, 0.f);
}

__global__ __launch_bounds__(256) void h0ln_kernel(const float* __restrict__ ne,
                                                   const int* __restrict__ idx,
                                                   const float* __restrict__ oov,
                                                   const float* __restrict__ g,
                                                   const float* __restrict__ b,
                                                   float* __restrict__ out) {
  __shared__ float sb[4];
  const int bi = blockIdx.x, t = threadIdx.x;
  const float v = (idx[bi] >= 0) ? ne[(size_t)bi * GNN_C + t] : oov[t];
  float s = v;
  for (int o = 32; o; o >>= 1) s += __shfl_down(s, o, 64);
  if ((t & 63) == 0) sb[t >> 6] = s;
  __syncthreads();
  const float m = (sb[0] + sb[1] + sb[2] + sb[3]) * (1.f / GNN_C);
  __syncthreads();
  const float d = v - m;
  s = d * d;
  for (int o = 32; o; o >>= 1) s += __shfl_down(s, o, 64);
  if ((t & 63) == 0) sb[t >> 6] = s;
  __syncthreads();
  const float rs = rsqrtf((sb[0] + sb[1] + sb[2] + sb[3]) * (1.f / GNN_C) + LN_EPS);
  out[(size_t)bi * GNN_C + t] = d * rs * g[t] + b[t];
}

__global__ __launch_bounds__(256) void ln512_kernel(const float* __restrict__ in,
                                                    const float* __restrict__ g,
                                                    const float* __restrict__ b,
                                                    float* __restrict__ out) {
  __shared__ float sb[4];
  const int r = blockIdx.x, t = threadIdx.x;
  const float v0 = in[(size_t)r * HID_C + t];
  const float v1 = in[(size_t)r * HID_C + t + 256];
  float s = v0 + v1;
  for (int o = 32; o; o >>= 1) s += __shfl_down(s, o, 64);
  if ((t & 63) == 0) sb[t >> 6] = s;
  __syncthreads();
  const float m = (sb[0] + sb[1] + sb[2] + sb[3]) * (1.f / HID_C);
  __syncthreads();
  const float d0 = v0 - m, d1 = v1 - m;
  s = d0 * d0 + d1 * d1;
  for (int o = 32; o; o >>= 1) s += __shfl_down(s, o, 64);
  if ((t & 63) == 0) sb[t >> 6] = s;
  __syncthreads();
  const float rs = rsqrtf((sb[0] + sb[1] + sb[2] + sb[3]) * (1.f / HID_C) + LN_EPS);
  out[(size_t)r * HID_C + t] = d0 * rs * g[t] + b[t];
  out[(size_t)r * HID_C + t + 256] = d1 * rs * g[t + 256] + b[t + 256];
}

// ---------------- host ----------------

extern "C" void kernel_launch(void* const* d_in, const int* in_sizes, int n_in,
                              void* d_out, int out_size, void* d_ws, size_t ws_size,
                              hipStream_t stream) {
  const int* node_idx = (const int*)d_in[0];
  const int* e_src = (const int*)d_in[1];
  const int* e_dst = e_src + N_EDGES_C;
  const float* ew = (const float*)d_in[2];
  const float* frozen = (const float*)d_in[3];
  const float* W6 = (const float*)d_in[4];
  const float* b6 = (const float*)d_in[5];
  const float* g6 = (const float*)d_in[6];
  const float* bl6 = (const float*)d_in[7];
  const float* W7 = (const float*)d_in[8];
  const float* b7 = (const float*)d_in[9];
  const float* g7 = (const float*)d_in[10];
  const float* bl7 = (const float*)d_in[11];
  const float* postW = (const float*)d_in[12];
  const float* postb = (const float*)d_in[13];
  const float* oov = (const float*)d_in[14];
  const float* ing = (const float*)d_in[15];
  const float* inb = (const float*)d_in[16];
  const float* projW = (const float*)d_in[17];
  const float* projb = (const float*)d_in[18];
  const float* rbg = (const float*)d_in[19];
  const float* rbb = (const float*)d_in[20];
  const float* rbW1 = (const float*)d_in[21];
  const float* rbb1 = (const float*)d_in[22];
  const float* rbW2 = (const float*)d_in[23];
  const float* rbb2 = (const float*)d_in[24];
  const float* outg = (const float*)d_in[25];
  const float* outb = (const float*)d_in[26];
  const float* bilW = (const float*)d_in[27];
  const float* bilb = (const float*)d_in[28];
  const float* gene = (const float*)d_in[29];
  (void)in_sizes; (void)n_in; (void)out_size; (void)ws_size;

  char* ws = (char*)d_ws;
  size_t o = 0;
  auto alloc = [&](size_t bytes) -> char* {
    char* p = ws + o;
    o += (bytes + 255) & ~(size_t)255;
    return p;
  };
  int* cnt = (int*)alloc((size_t)N_NODES_C * 4);
  int* off = (int*)alloc((size_t)(N_NODES_C + 1) * 4);
  int* cur = (int*)alloc((size_t)N_NODES_C * 4);
  int* bsrc = (int*)alloc((size_t)N_EDGES_C * 4);
  float* bw = (float*)alloc((size_t)N_EDGES_C * 4);
  float* agg6 = (float*)alloc((size_t)N_NODES_C * GNN_C * 4);
  float* y6 = (float*)alloc((size_t)N_NODES_C * GNN_C * 4);
  float* agg7b = (float*)alloc((size_t)B_C * GNN_C * 4);
  float* y7b = (float*)alloc((size_t)B_C * GNN_C * 4);
  float* x2b = (float*)alloc((size_t)B_C * GNN_C * 4);
  float* nemb = (float*)alloc((size_t)B_C * GNN_C * 4);
  float* h0l = (float*)alloc((size_t)B_C * GNN_C * 4);
  float* h = (float*)alloc((size_t)B_C * HID_C * 4);
  float* tb = (float*)alloc((size_t)B_C * HID_C * 4);
  float* u = (float*)alloc((size_t)B_C * 4 * HID_C * 4);
  float* hl = (float*)alloc((size_t)B_C * HID_C * 4);
  float* pert = (float*)alloc((size_t)B_C * NCLS_C * RANK_C * 4);
  float* part = (float*)alloc((size_t)8 * B_C * 2048 * 4);  // split-K partials (max 16 MB)
  float* x1f = agg6;  // alias: agg6 dead after conv6 GEMM

  // CSR build
  (void)hipMemsetAsync(cnt, 0, (size_t)N_NODES_C * 4, stream);
  (void)hipMemsetAsync(cur, 0, (size_t)N_NODES_C * 4, stream);
  const int egrid = (N_EDGES_C + 255) / 256;
  hist_kernel<<<egrid, 256, 0, stream>>>(e_dst, cnt, N_EDGES_C);
  scan_kernel<<<1, 1024, 0, stream>>>(cnt, off, N_NODES_C);
  fill_kernel<<<egrid, 256, 0, stream>>>(e_src, e_dst, ew, off, cur, bsrc, bw, N_EDGES_C);

  // helper: split-K GEMM + combine
  auto sk = [&](const float* A, const float* Bm, const float* bias, const float* resid,
                float* out, int M, int N, int K, int S, int op) {
    const int kChunk = K / S;
    dim3 g(M / 64, N / 64, S);
    skgemm_kernel<<<g, 256, 0, stream>>>(A, Bm, part, M, N, K, kChunk);
    const int MN = M * N;
    combine_kernel<<<(MN + 255) / 256, 256, 0, stream>>>(part, S, MN, N, bias, resid, out, op);
  };

  // conv6 (full graph)
  agg_full_kernel<<<N_NODES_C, 256, 0, stream>>>(bsrc, bw, off, frozen, agg6);
  {
    dim3 g((N_NODES_C + 63) / 64, GNN_C / 64);
    gemm_kernel<<<g, 256, 0, stream>>>(agg6, W6, b6, nullptr, y6,
                                       N_NODES_C, GNN_C, GNN_C, 0, 0);
  }
  postconv6_kernel<<<N_NODES_C, 256, 0, stream>>>(y6, g6, bl6, frozen, x1f);

  // conv7 (only the B gathered nodes)
  agg_sel_kernel<<<B_C, 256, 0, stream>>>(node_idx, bsrc, bw, off, x1f, agg7b);
  sk(agg7b, W7, b7, nullptr, y7b, B_C, GNN_C, GNN_C, 8, 0);
  postconv7_kernel<<<B_C, 256, 0, stream>>>(y7b, g7, bl7, node_idx, x1f, x2b);

  // node_emb = x2 @ post_W + post_b (B rows only)
  sk(x2b, postW, postb, nullptr, nemb, B_C, GNN_C, GNN_C, 8, 0);
  h0ln_kernel<<<B_C, 256, 0, stream>>>(nemb, node_idx, oov, ing, inb, h0l);

  // proj_in
  sk(h0l, projW, projb, nullptr, h, B_C, HID_C, GNN_C, 8, 0);

  // residual blocks
  for (int i = 0; i < NBLK_C; ++i) {
    ln512_kernel<<<B_C, 256, 0, stream>>>(h, rbg + (size_t)i * HID_C,
                                          rbb + (size_t)i * HID_C, tb);
    sk(tb, rbW1 + (size_t)i * HID_C * 4 * HID_C, rbb1 + (size_t)i * 4 * HID_C,
       nullptr, u, B_C, 4 * HID_C, HID_C, 2, 1);
    sk(u, rbW2 + (size_t)i * 4 * HID_C * HID_C, rbb2 + (size_t)i * HID_C,
       h, h, B_C, HID_C, 4 * HID_C, 8, 2);
  }

  // out_ln + bilinear
  ln512_kernel<<<B_C, 256, 0, stream>>>(h, outg, outb, hl);
  sk(hl, bilW, bilb, nullptr, pert, B_C, NCLS_C * RANK_C, HID_C, 4, 0);

  // logits = pert([768,512]) @ gene^T ([512,6640]) -> fp32 d_out
  {
    dim3 g((B_C * NCLS_C + 63) / 64, (NGENES_C + 63) / 64);
    gemm_kernel<<<g, 256, 0, stream>>>(pert, gene, nullptr, nullptr,
                                       (float*)d_out, B_C * NCLS_C, NGENES_C, RANK_C, 1, 0);
  }
}

// Round 4
// 907.625 us; speedup vs baseline: 2.1545x; 1.1090x over previous
//
#include <hip/hip_runtime.h>
#include <hip/hip_bf16.h>
#include <cstdint>
#include <cstddef>

#define N_NODES_C 19385
#define N_EDGES_C 1200000
#define GNN_C 256
#define HID_C 512
#define RANK_C 512
#define NCLS_C 3
#define NGENES_C 6640
#define NBLK_C 6
#define B_C 256
#define LN_EPS 1e-5f

typedef short bf8v __attribute__((ext_vector_type(8)));
typedef float f4v __attribute__((ext_vector_type(4)));

__device__ __forceinline__ float bfu2f(unsigned short u) {
  union { unsigned int i; float f; } c; c.i = ((unsigned)u) << 16; return c.f;
}
__device__ __forceinline__ unsigned short f2bfu(float v) {
  union { float f; unsigned u; } c; c.f = v;
  unsigned r = c.u + 0x7FFFu + ((c.u >> 16) & 1u);
  return (unsigned short)(r >> 16);
}

// ---------------- dtype convert ----------------

__global__ __launch_bounds__(256) void f2bf_kernel(const float* __restrict__ in,
                                                   unsigned short* __restrict__ out, int n) {
  int i = blockIdx.x * 256 + threadIdx.x;
  if (i < n) out[i] = f2bfu(in[i]);
}

// ---------------- CSR build ----------------

__global__ __launch_bounds__(256) void hist_kernel(const int* __restrict__ dst,
                                                   int* __restrict__ cnt, int E) {
  int i = blockIdx.x * 256 + threadIdx.x;
  if (i < E) atomicAdd(&cnt[dst[i]], 1);
}

__global__ __launch_bounds__(1024) void scan_kernel(const int* __restrict__ cnt,
                                                    int* __restrict__ off, int n) {
  __shared__ int sums[1024];
  const int t = threadIdx.x;
  const int CH = (n + 1023) >> 10;
  const int base = t * CH;
  int s = 0;
  for (int i = 0; i < CH; ++i) {
    int idx = base + i;
    if (idx < n) s += cnt[idx];
  }
  sums[t] = s;
  __syncthreads();
  for (int d = 1; d < 1024; d <<= 1) {
    int v = (t >= d) ? sums[t - d] : 0;
    __syncthreads();
    sums[t] += v;
    __syncthreads();
  }
  int run = (t == 0) ? 0 : sums[t - 1];
  for (int i = 0; i < CH; ++i) {
    int idx = base + i;
    if (idx < n) { off[idx] = run; run += cnt[idx]; }
  }
  if (t == 0) off[n] = sums[1023];
}

__global__ __launch_bounds__(256) void fill_kernel(const int* __restrict__ src,
                                                   const int* __restrict__ dst,
                                                   const float* __restrict__ ew,
                                                   const int* __restrict__ off,
                                                   int* __restrict__ cur,
                                                   int* __restrict__ bsrc,
                                                   float* __restrict__ bw, int E) {
  int i = blockIdx.x * 256 + threadIdx.x;
  if (i < E) {
    int d = dst[i];
    int p = atomicAdd(&cur[d], 1);
    int q = off[d] + p;
    bsrc[q] = src[i] * GNN_C;
    bw[q] = ew[i];
  }
}

// ---------------- edge aggregation ----------------

// bf16 gather, fp32 accumulate, bf16 output (feeds MFMA GEMM)
__global__ __launch_bounds__(256) void agg_full_kernel(const int* __restrict__ bsrc,
                                                       const float* __restrict__ bw,
                                                       const int* __restrict__ off,
                                                       const unsigned short* __restrict__ x,
                                                       unsigned short* __restrict__ aggbf) {
  __shared__ int ss[64];
  __shared__ float sw[64];
  const int n = blockIdx.x;
  const int t = threadIdx.x;
  const int s0 = off[n], s1 = off[n + 1];
  float acc = 0.f;
  for (int pos = s0; pos < s1; pos += 64) {
    const int cnt = min(64, s1 - pos);
    __syncthreads();
    if (t < cnt) { ss[t] = bsrc[pos + t]; sw[t] = bw[pos + t]; }
    __syncthreads();
    int j = 0;
    for (; j + 3 < cnt; j += 4) {
      const float x0 = bfu2f(x[ss[j + 0] + t]);
      const float x1 = bfu2f(x[ss[j + 1] + t]);
      const float x2 = bfu2f(x[ss[j + 2] + t]);
      const float x3 = bfu2f(x[ss[j + 3] + t]);
      acc = fmaf(x0, sw[j + 0], acc);
      acc = fmaf(x1, sw[j + 1], acc);
      acc = fmaf(x2, sw[j + 2], acc);
      acc = fmaf(x3, sw[j + 3], acc);
    }
    for (; j < cnt; ++j) acc = fmaf(bfu2f(x[ss[j] + t]), sw[j], acc);
  }
  aggbf[(size_t)n * GNN_C + t] = f2bfu(acc);
}

// restricted aggregation over fp32 x1 (tiny: ~16K edges)
__global__ __launch_bounds__(256) void agg_sel_kernel(const int* __restrict__ node_idx,
                                                      const int* __restrict__ bsrc,
                                                      const float* __restrict__ bw,
                                                      const int* __restrict__ off,
                                                      const float* __restrict__ x,
                                                      float* __restrict__ agg) {
  __shared__ int ss[64];
  __shared__ float sw[64];
  const int b = blockIdx.x;
  const int t = threadIdx.x;
  const int n = max(node_idx[b], 0);
  const int s0 = off[n], s1 = off[n + 1];
  float acc = 0.f;
  for (int pos = s0; pos < s1; pos += 64) {
    const int cnt = min(64, s1 - pos);
    __syncthreads();
    if (t < cnt) { ss[t] = bsrc[pos + t]; sw[t] = bw[pos + t]; }
    __syncthreads();
    for (int j = 0; j < cnt; ++j) acc = fmaf(x[ss[j] + t], sw[j], acc);
  }
  agg[(size_t)b * GNN_C + t] = acc;
}

// ---------------- MFMA bf16 GEMM: C(fp32) = A(bf16)[M,K] @ B(bf16) (+bias) ----------------
// 128x128 tile, BK=32, 4 waves (2x2), each wave 64x64 = 4x4 frags of 16x16x32

#define MBK 32
#define MLDW 40   // +8 pad: row stride 80B kills the 64B-stride 8-way bank conflict

__global__ __launch_bounds__(256) void mgemm_kernel(const unsigned short* __restrict__ A,
                                                    const unsigned short* __restrict__ B,
                                                    const float* __restrict__ bias,
                                                    float* __restrict__ C,
                                                    int M, int N, int K, int transB) {
  __shared__ unsigned short As[128][MLDW];
  __shared__ unsigned short Bs[128][MLDW];
  const int t = threadIdx.x;
  const int lane = t & 63;
  const int wave = t >> 6;
  const int r0 = blockIdx.x * 128;
  const int c0 = blockIdx.y * 128;
  const int wm = (wave >> 1) * 64;
  const int wn = (wave & 1) * 64;
  const int lm = lane & 15;
  const int lq = lane >> 4;

  f4v acc[4][4];
  for (int i = 0; i < 4; ++i)
    for (int j = 0; j < 4; ++j)
      for (int r = 0; r < 4; ++r) acc[i][j][r] = 0.f;

  for (int k0 = 0; k0 < K; k0 += MBK) {
    // stage A: thread t loads 16 bf16 of row t>>1 at kof=(t&1)*16
    {
      const int row = t >> 1;
      const int kof = (t & 1) * 16;
      const int gr = r0 + row;
      uint4 u0 = make_uint4(0, 0, 0, 0), u1 = u0;
      if (gr < M) {
        const uint4* p = reinterpret_cast<const uint4*>(A + (size_t)gr * K + k0 + kof);
        u0 = p[0]; u1 = p[1];
      }
      *reinterpret_cast<uint4*>(&As[row][kof]) = u0;
      *reinterpret_cast<uint4*>(&As[row][kof + 8]) = u1;
    }
    // stage B into Bs[n][k]
    if (transB) {
      const int row = t >> 1;
      const int kof = (t & 1) * 16;
      const int gn = c0 + row;
      uint4 u0 = make_uint4(0, 0, 0, 0), u1 = u0;
      if (gn < N) {
        const uint4* p = reinterpret_cast<const uint4*>(B + (size_t)gn * K + k0 + kof);
        u0 = p[0]; u1 = p[1];
      }
      *reinterpret_cast<uint4*>(&Bs[row][kof]) = u0;
      *reinterpret_cast<uint4*>(&Bs[row][kof + 8]) = u1;
    } else {
      const int n = t & 127;
      const int kb = (t >> 7) * 16;
      const int gn = c0 + n;
      union { unsigned short s[16]; uint4 q[2]; } tmp;
      if (gn < N) {
        for (int i = 0; i < 16; ++i) tmp.s[i] = B[(size_t)(k0 + kb + i) * N + gn];
      } else {
        for (int i = 0; i < 16; ++i) tmp.s[i] = 0;
      }
      *reinterpret_cast<uint4*>(&Bs[n][kb]) = tmp.q[0];
      *reinterpret_cast<uint4*>(&Bs[n][kb + 8]) = tmp.q[1];
    }
    __syncthreads();

    bf8v a[4], b[4];
#pragma unroll
    for (int i = 0; i < 4; ++i)
      a[i] = *reinterpret_cast<const bf8v*>(&As[wm + i * 16 + lm][lq * 8]);
#pragma unroll
    for (int j = 0; j < 4; ++j)
      b[j] = *reinterpret_cast<const bf8v*>(&Bs[wn + j * 16 + lm][lq * 8]);
#pragma unroll
    for (int i = 0; i < 4; ++i)
#pragma unroll
      for (int j = 0; j < 4; ++j)
        acc[i][j] = __builtin_amdgcn_mfma_f32_16x16x32_bf16(a[i], b[j], acc[i][j], 0, 0, 0);
    __syncthreads();
  }

  // epilogue: C/D layout col=lane&15, row=(lane>>4)*4+reg
  for (int ti = 0; ti < 4; ++ti) {
    for (int tj = 0; tj < 4; ++tj) {
      const int col = c0 + wn + tj * 16 + lm;
      if (col >= N) continue;
      const float bv = bias ? bias[col] : 0.f;
      for (int r = 0; r < 4; ++r) {
        const int row = r0 + wm + ti * 16 + lq * 4 + r;
        if (row < M) C[(size_t)row * N + col] = acc[ti][tj][r] + bv;
      }
    }
  }
}

// ---------------- fp32 vector GEMM (head, split-K) ----------------

#define KC 32

__device__ __forceinline__ void gemm_tile_body(const float* __restrict__ A,
                                               const float* __restrict__ B,
                                               int M, int N, int K,
                                               int r0, int c0, int kBeg, int kEnd,
                                               int t,
                                               float (&acc)[4][4],
                                               float (*As)[72], float (*Bs)[72]) {
  const int tx = t & 15;
  const int ty = t >> 4;
  for (int k0 = kBeg; k0 < kEnd; k0 += KC) {
    {
      const int ra = t >> 2;
      const int kk = (t & 3) * 8;
      const int gr = r0 + ra;
      float4 v0, v1;
      if (gr < M) {
        const float4* p = reinterpret_cast<const float4*>(A + (size_t)gr * K + k0 + kk);
        v0 = p[0]; v1 = p[1];
      } else {
        v0 = make_float4(0.f, 0.f, 0.f, 0.f); v1 = v0;
      }
      As[kk + 0][ra] = v0.x; As[kk + 1][ra] = v0.y;
      As[kk + 2][ra] = v0.z; As[kk + 3][ra] = v0.w;
      As[kk + 4][ra] = v1.x; As[kk + 5][ra] = v1.y;
      As[kk + 6][ra] = v1.z; As[kk + 7][ra] = v1.w;
    }
    {
      const int c = (t & 15) * 4;
      const int kk = (t >> 4) * 2;
      for (int j = 0; j < 2; ++j) {
        const int gk = k0 + kk + j;
        const int gc = c0 + c;
        float4 bv;
        if (gc + 3 < N) {
          bv = *reinterpret_cast<const float4*>(B + (size_t)gk * N + gc);
        } else {
          bv.x = (gc + 0 < N) ? B[(size_t)gk * N + gc + 0] : 0.f;
          bv.y = (gc + 1 < N) ? B[(size_t)gk * N + gc + 1] : 0.f;
          bv.z = (gc + 2 < N) ? B[(size_t)gk * N + gc + 2] : 0.f;
          bv.w = (gc + 3 < N) ? B[(size_t)gk * N + gc + 3] : 0.f;
        }
        *reinterpret_cast<float4*>(&Bs[kk + j][c]) = bv;
      }
    }
    __syncthreads();
#pragma unroll
    for (int kk = 0; kk < KC; ++kk) {
      const float4 a = *reinterpret_cast<const float4*>(&As[kk][ty * 4]);
      const float4 b = *reinterpret_cast<const float4*>(&Bs[kk][tx * 4]);
      acc[0][0] = fmaf(a.x, b.x, acc[0][0]);
      acc[0][1] = fmaf(a.x, b.y, acc[0][1]);
      acc[0][2] = fmaf(a.x, b.z, acc[0][2]);
      acc[0][3] = fmaf(a.x, b.w, acc[0][3]);
      acc[1][0] = fmaf(a.y, b.x, acc[1][0]);
      acc[1][1] = fmaf(a.y, b.y, acc[1][1]);
      acc[1][2] = fmaf(a.y, b.z, acc[1][2]);
      acc[1][3] = fmaf(a.y, b.w, acc[1][3]);
      acc[2][0] = fmaf(a.z, b.x, acc[2][0]);
      acc[2][1] = fmaf(a.z, b.y, acc[2][1]);
      acc[2][2] = fmaf(a.z, b.z, acc[2][2]);
      acc[2][3] = fmaf(a.z, b.w, acc[2][3]);
      acc[3][0] = fmaf(a.w, b.x, acc[3][0]);
      acc[3][1] = fmaf(a.w, b.y, acc[3][1]);
      acc[3][2] = fmaf(a.w, b.z, acc[3][2]);
      acc[3][3] = fmaf(a.w, b.w, acc[3][3]);
    }
    __syncthreads();
  }
}

__global__ __launch_bounds__(256) void skgemm_kernel(const float* __restrict__ A,
                                                     const float* __restrict__ B,
                                                     float* __restrict__ part,
                                                     int M, int N, int K, int kChunk) {
  __shared__ float As[KC][72];
  __shared__ float Bs[KC][72];
  const int t = threadIdx.x;
  const int r0 = blockIdx.x * 64;
  const int c0 = blockIdx.y * 64;
  const int kBeg = blockIdx.z * kChunk;
  const int kEnd = min(K, kBeg + kChunk);
  float acc[4][4] = {{0.f}};
  gemm_tile_body(A, B, M, N, K, r0, c0, kBeg, kEnd, t, acc, As, Bs);
  float* out = part + (size_t)blockIdx.z * M * N;
  const int tx = t & 15, ty = t >> 4;
  for (int i = 0; i < 4; ++i) {
    const int row = r0 + ty * 4 + i;
    for (int j = 0; j < 4; ++j) {
      const int col = c0 + tx * 4 + j;
      out[(size_t)row * N + col] = acc[i][j];
    }
  }
}

__global__ __launch_bounds__(256) void combine_kernel(const float* __restrict__ part,
                                                      int S, int MN, int N,
                                                      const float* __restrict__ bias,
                                                      const float* __restrict__ resid,
                                                      float* __restrict__ out, int op) {
  int i = blockIdx.x * 256 + threadIdx.x;
  if (i >= MN) return;
  float v = 0.f;
  for (int s = 0; s < S; ++s) v += part[(size_t)s * MN + i];
  v += bias[i - (i / N) * N];
  if (op == 1) {
    const float x3 = v * v * v;
    v = 0.5f * v * (1.f + tanhf(0.7978845608028654f * (v + 0.044715f * x3)));
  } else if (op == 2) {
    v += resid[i];
  }
  out[i] = v;
}

// ---------------- LN family ----------------

__global__ __launch_bounds__(256) void postconv6_kernel(const float* __restrict__ y,
                                                        const float* __restrict__ g,
                                                        const float* __restrict__ b,
                                                        const float* __restrict__ frozen,
                                                        float* __restrict__ x1f) {
  __shared__ float sb[4];
  const int n = blockIdx.x, t = threadIdx.x;
  const float v = y[(size_t)n * GNN_C + t];
  float s = v;
  for (int o = 32; o; o >>= 1) s += __shfl_down(s, o, 64);
  if ((t & 63) == 0) sb[t >> 6] = s;
  __syncthreads();
  const float m = (sb[0] + sb[1] + sb[2] + sb[3]) * (1.f / GNN_C);
  __syncthreads();
  const float d = v - m;
  s = d * d;
  for (int o = 32; o; o >>= 1) s += __shfl_down(s, o, 64);
  if ((t & 63) == 0) sb[t >> 6] = s;
  __syncthreads();
  const float rs = rsqrtf((sb[0] + sb[1] + sb[2] + sb[3]) * (1.f / GNN_C) + LN_EPS);
  const float xn = d * rs * g[t] + b[t];
  x1f[(size_t)n * GNN_C + t] = frozen[(size_t)n * GNN_C + t] + fmaxf(xn, 0.f);
}

__global__ __launch_bounds__(256) void postconv7_kernel(const float* __restrict__ y,
                                                        const float* __restrict__ g,
                                                        const float* __restrict__ b,
                                                        const int* __restrict__ idx,
                                                        const float* __restrict__ x1f,
                                                        float* __restrict__ out) {
  __shared__ float sb[4];
  const int bi = blockIdx.x, t = threadIdx.x;
  const int n = max(idx[bi], 0);
  const float v = y[(size_t)bi * GNN_C + t];
  float s = v;
  for (int o = 32; o; o >>= 1) s += __shfl_down(s, o, 64);
  if ((t & 63) == 0) sb[t >> 6] = s;
  __syncthreads();
  const float m = (sb[0] + sb[1] + sb[2] + sb[3]) * (1.f / GNN_C);
  __syncthreads();
  const float d = v - m;
  s = d * d;
  for (int o = 32; o; o >>= 1) s += __shfl_down(s, o, 64);
  if ((t & 63) == 0) sb[t >> 6] = s;
  __syncthreads();
  const float rs = rsqrtf((sb[0] + sb[1] + sb[2] + sb[3]) * (1.f / GNN_C) + LN_EPS);
  const float xn = d * rs * g[t] + b[t];
  out[(size_t)bi * GNN_C + t] = x1f[(size_t)n * GNN_C + t] + fmaxf(xn, 0.f);
}

__global__ __launch_bounds__(256) void h0ln_kernel(const float* __restrict__ ne,
                                                   const int* __restrict__ idx,
                                                   const float* __restrict__ oov,
                                                   const float* __restrict__ g,
                                                   const float* __restrict__ b,
                                                   float* __restrict__ out) {
  __shared__ float sb[4];
  const int bi = blockIdx.x, t = threadIdx.x;
  const float v = (idx[bi] >= 0) ? ne[(size_t)bi * GNN_C + t] : oov[t];
  float s = v;
  for (int o = 32; o; o >>= 1) s += __shfl_down(s, o, 64);
  if ((t & 63) == 0) sb[t >> 6] = s;
  __syncthreads();
  const float m = (sb[0] + sb[1] + sb[2] + sb[3]) * (1.f / GNN_C);
  __syncthreads();
  const float d = v - m;
  s = d * d;
  for (int o = 32; o; o >>= 1) s += __shfl_down(s, o, 64);
  if ((t & 63) == 0) sb[t >> 6] = s;
  __syncthreads();
  const float rs = rsqrtf((sb[0] + sb[1] + sb[2] + sb[3]) * (1.f / GNN_C) + LN_EPS);
  out[(size_t)bi * GNN_C + t] = d * rs * g[t] + b[t];
}

__global__ __launch_bounds__(256) void ln512_kernel(const float* __restrict__ in,
                                                    const float* __restrict__ g,
                                                    const float* __restrict__ b,
                                                    float* __restrict__ out) {
  __shared__ float sb[4];
  const int r = blockIdx.x, t = threadIdx.x;
  const float v0 = in[(size_t)r * HID_C + t];
  const float v1 = in[(size_t)r * HID_C + t + 256];
  float s = v0 + v1;
  for (int o = 32; o; o >>= 1) s += __shfl_down(s, o, 64);
  if ((t & 63) == 0) sb[t >> 6] = s;
  __syncthreads();
  const float m = (sb[0] + sb[1] + sb[2] + sb[3]) * (1.f / HID_C);
  __syncthreads();
  const float d0 = v0 - m, d1 = v1 - m;
  s = d0 * d0 + d1 * d1;
  for (int o = 32; o; o >>= 1) s += __shfl_down(s, o, 64);
  if ((t & 63) == 0) sb[t >> 6] = s;
  __syncthreads();
  const float rs = rsqrtf((sb[0] + sb[1] + sb[2] + sb[3]) * (1.f / HID_C) + LN_EPS);
  out[(size_t)r * HID_C + t] = d0 * rs * g[t] + b[t];
  out[(size_t)r * HID_C + t + 256] = d1 * rs * g[t + 256] + b[t + 256];
}

// ---------------- host ----------------

extern "C" void kernel_launch(void* const* d_in, const int* in_sizes, int n_in,
                              void* d_out, int out_size, void* d_ws, size_t ws_size,
                              hipStream_t stream) {
  const int* node_idx = (const int*)d_in[0];
  const int* e_src = (const int*)d_in[1];
  const int* e_dst = e_src + N_EDGES_C;
  const float* ew = (const float*)d_in[2];
  const float* frozen = (const float*)d_in[3];
  const float* W6 = (const float*)d_in[4];
  const float* b6 = (const float*)d_in[5];
  const float* g6 = (const float*)d_in[6];
  const float* bl6 = (const float*)d_in[7];
  const float* W7 = (const float*)d_in[8];
  const float* b7 = (const float*)d_in[9];
  const float* g7 = (const float*)d_in[10];
  const float* bl7 = (const float*)d_in[11];
  const float* postW = (const float*)d_in[12];
  const float* postb = (const float*)d_in[13];
  const float* oov = (const float*)d_in[14];
  const float* ing = (const float*)d_in[15];
  const float* inb = (const float*)d_in[16];
  const float* projW = (const float*)d_in[17];
  const float* projb = (const float*)d_in[18];
  const float* rbg = (const float*)d_in[19];
  const float* rbb = (const float*)d_in[20];
  const float* rbW1 = (const float*)d_in[21];
  const float* rbb1 = (const float*)d_in[22];
  const float* rbW2 = (const float*)d_in[23];
  const float* rbb2 = (const float*)d_in[24];
  const float* outg = (const float*)d_in[25];
  const float* outb = (const float*)d_in[26];
  const float* bilW = (const float*)d_in[27];
  const float* bilb = (const float*)d_in[28];
  const float* gene = (const float*)d_in[29];
  (void)in_sizes; (void)n_in; (void)out_size; (void)ws_size;

  char* ws = (char*)d_ws;
  size_t o = 0;
  auto alloc = [&](size_t bytes) -> char* {
    char* p = ws + o;
    o += (bytes + 255) & ~(size_t)255;
    return p;
  };
  int* cnt = (int*)alloc((size_t)N_NODES_C * 4);
  int* off = (int*)alloc((size_t)(N_NODES_C + 1) * 4);
  int* cur = (int*)alloc((size_t)N_NODES_C * 4);
  int* bsrc = (int*)alloc((size_t)N_EDGES_C * 4);
  float* bw = (float*)alloc((size_t)N_EDGES_C * 4);
  unsigned short* frozbf = (unsigned short*)alloc((size_t)N_NODES_C * GNN_C * 2);
  unsigned short* agg6bf = (unsigned short*)alloc((size_t)N_NODES_C * GNN_C * 2);
  unsigned short* w6bf = (unsigned short*)alloc((size_t)GNN_C * GNN_C * 2);
  float* y6 = (float*)alloc((size_t)N_NODES_C * GNN_C * 4);  // reused as head region
  float* x1f = (float*)alloc((size_t)N_NODES_C * GNN_C * 4);

  // aliases (live ranges verified):
  unsigned short* genebf = frozbf;  // frozbf dead after agg_full
  unsigned short* pertbf = agg6bf;  // agg6bf dead after conv6 mgemm
  // head buffers carved from y6 region (y6 dead after postconv6; 19.9 MB available)
  char* hr = (char*)y6;
  size_t ho = 0;
  auto halloc = [&](size_t bytes) -> char* {
    char* p = hr + ho;
    ho += (bytes + 255) & ~(size_t)255;
    return p;
  };
  float* part = (float*)halloc((size_t)4 * B_C * NCLS_C * RANK_C * 4);  // max S*M*N = 6.3 MB
  float* agg7b = (float*)halloc((size_t)B_C * GNN_C * 4);
  float* y7b = (float*)halloc((size_t)B_C * GNN_C * 4);
  float* x2b = (float*)halloc((size_t)B_C * GNN_C * 4);
  float* nemb = (float*)halloc((size_t)B_C * GNN_C * 4);
  float* h0l = (float*)halloc((size_t)B_C * GNN_C * 4);
  float* h = (float*)halloc((size_t)B_C * HID_C * 4);
  float* tb = (float*)halloc((size_t)B_C * HID_C * 4);
  float* u = (float*)halloc((size_t)B_C * 4 * HID_C * 4);
  float* hl = (float*)halloc((size_t)B_C * HID_C * 4);
  float* pert = (float*)halloc((size_t)B_C * NCLS_C * RANK_C * 4);

  // CSR build
  (void)hipMemsetAsync(cnt, 0, (size_t)N_NODES_C * 4, stream);
  (void)hipMemsetAsync(cur, 0, (size_t)N_NODES_C * 4, stream);
  const int egrid = (N_EDGES_C + 255) / 256;
  hist_kernel<<<egrid, 256, 0, stream>>>(e_dst, cnt, N_EDGES_C);
  scan_kernel<<<1, 1024, 0, stream>>>(cnt, off, N_NODES_C);
  fill_kernel<<<egrid, 256, 0, stream>>>(e_src, e_dst, ew, off, cur, bsrc, bw, N_EDGES_C);

  // converts for conv6
  {
    const int nf = N_NODES_C * GNN_C;
    f2bf_kernel<<<(nf + 255) / 256, 256, 0, stream>>>(frozen, frozbf, nf);
    const int nw = GNN_C * GNN_C;
    f2bf_kernel<<<(nw + 255) / 256, 256, 0, stream>>>(W6, w6bf, nw);
  }

  // conv6 (full graph): bf16 gather + MFMA GEMM
  agg_full_kernel<<<N_NODES_C, 256, 0, stream>>>(bsrc, bw, off, frozbf, agg6bf);
  {
    dim3 g((N_NODES_C + 127) / 128, GNN_C / 128);
    mgemm_kernel<<<g, 256, 0, stream>>>(agg6bf, w6bf, b6, y6, N_NODES_C, GNN_C, GNN_C, 0);
  }
  postconv6_kernel<<<N_NODES_C, 256, 0, stream>>>(y6, g6, bl6, frozen, x1f);

  // convert gene (after agg_full: aliases frozbf)
  {
    const int ng = NGENES_C * RANK_C;
    f2bf_kernel<<<(ng + 255) / 256, 256, 0, stream>>>(gene, genebf, ng);
  }

  auto sk = [&](const float* A, const float* Bm, const float* bias, const float* resid,
                float* out, int M, int N, int K, int S, int op) {
    const int kChunk = K / S;
    dim3 g(M / 64, N / 64, S);
    skgemm_kernel<<<g, 256, 0, stream>>>(A, Bm, part, M, N, K, kChunk);
    const int MN = M * N;
    combine_kernel<<<(MN + 255) / 256, 256, 0, stream>>>(part, S, MN, N, bias, resid, out, op);
  };

  // conv7 (only the B gathered nodes)
  agg_sel_kernel<<<B_C, 256, 0, stream>>>(node_idx, bsrc, bw, off, x1f, agg7b);
  sk(agg7b, W7, b7, nullptr, y7b, B_C, GNN_C, GNN_C, 8, 0);
  postconv7_kernel<<<B_C, 256, 0, stream>>>(y7b, g7, bl7, node_idx, x1f, x2b);

  // node_emb = x2 @ post_W + post_b
  sk(x2b, postW, postb, nullptr, nemb, B_C, GNN_C, GNN_C, 8, 0);
  h0ln_kernel<<<B_C, 256, 0, stream>>>(nemb, node_idx, oov, ing, inb, h0l);

  // proj_in
  sk(h0l, projW, projb, nullptr, h, B_C, HID_C, GNN_C, 8, 0);

  // residual blocks
  for (int i = 0; i < NBLK_C; ++i) {
    ln512_kernel<<<B_C, 256, 0, stream>>>(h, rbg + (size_t)i * HID_C,
                                          rbb + (size_t)i * HID_C, tb);
    sk(tb, rbW1 + (size_t)i * HID_C * 4 * HID_C, rbb1 + (size_t)i * 4 * HID_C,
       nullptr, u, B_C, 4 * HID_C, HID_C, 2, 1);
    sk(u, rbW2 + (size_t)i * 4 * HID_C * HID_C, rbb2 + (size_t)i * HID_C,
       h, h, B_C, HID_C, 4 * HID_C, 8, 2);
  }

  // out_ln + bilinear
  ln512_kernel<<<B_C, 256, 0, stream>>>(h, outg, outb, hl);
  sk(hl, bilW, bilb, nullptr, pert, B_C, NCLS_C * RANK_C, HID_C, 4, 0);

  // final einsum as MFMA GEMM: pert[768,512] @ gene^T -> d_out fp32
  {
    const int np = B_C * NCLS_C * RANK_C;
    f2bf_kernel<<<(np + 255) / 256, 256, 0, stream>>>(pert, pertbf, np);
    dim3 g((B_C * NCLS_C) / 128, (NGENES_C + 127) / 128);
    mgemm_kernel<<<g, 256, 0, stream>>>(pertbf, genebf, nullptr, (float*)d_out,
                                        B_C * NCLS_C, NGENES_C, RANK_C, 1);
  }
}